// Round 1
// baseline (11763.418 us; speedup 1.0000x reference)
//
#include <hip/hip_runtime.h>
#include <math.h>

typedef unsigned short u16;
typedef unsigned int u32;

#define NSYN 37
#define NB   2048
#define KS   296
#define TSTEPS 2000
#define SFRAMES 200
#define BATCH 32
#define HID 256
#define OUTC 39

// ws layout (byte offsets, all 16B aligned)
#define WS_W      0u          // float [2][37][2048]
#define WS_IDX    606208u     // u16   [2][37][2048]
#define WS_BETA   909312u     // float [2][2048]
#define WS_CB     925696u     // float [2][2048]
#define WS_ALPHA  942080u     // float [2][256]
#define WS_FRAMES 944128u     // float [2][32][200][256]
#define WS_Y      14051328u   // float [200][32][39]

// ---------------------------------------------------------------- setup ----
__global__ void build_sparse(
    const float* __restrict__ w_fw, const float* __restrict__ b_fw,
    const float* __restrict__ tau_n_fw, const float* __restrict__ mask_fw,
    const float* __restrict__ w_bw, const float* __restrict__ b_bw,
    const float* __restrict__ tau_n_bw, const float* __restrict__ mask_bw,
    const float* __restrict__ tau_m_fw, const float* __restrict__ tau_m_bw,
    float* __restrict__ W, u16* __restrict__ IDX, float* __restrict__ BETA,
    float* __restrict__ CB, float* __restrict__ ALPHA)
{
  const int rid = blockIdx.x * 256 + threadIdx.x;
  if (rid < 2 * NB) {
    const int dir = rid >> 11, r = rid & (NB - 1);
    const float* w  = dir ? w_bw : w_fw;
    const float* mk = dir ? mask_bw : mask_fw;
    const float* bb = dir ? b_bw : b_fw;
    const float* tn = dir ? tau_n_bw : tau_n_fw;
    u16 jj[NSYN]; float wv[NSYN];
    int cnt = 0;
    for (int j = 0; j < KS; ++j) {
      const float m = mk[(size_t)r * KS + j];
      if (m != 0.0f && cnt < NSYN) { jj[cnt] = (u16)j; wv[cnt] = w[(size_t)r * KS + j]; ++cnt; }
    }
    for (; cnt < NSYN; ++cnt) { jj[cnt] = (u16)(KS - 1); wv[cnt] = 0.0f; }
    // sort synapses by LDS bank rotated by branch index -> spread banks per slot
    const int rot = r & 31;
    for (int i = 1; i < NSYN; ++i) {
      const u16 kj = jj[i]; const float kw = wv[i];
      const int key = ((kj & 31) - rot) & 31;
      int p = i - 1;
      while (p >= 0 && ((((jj[p] & 31) - rot) & 31) > key)) {
        jj[p + 1] = jj[p]; wv[p + 1] = wv[p]; --p;
      }
      jj[p + 1] = kj; wv[p + 1] = kw;
    }
    for (int s = 0; s < NSYN; ++s) {
      W[((size_t)dir * NSYN + s) * NB + r]   = wv[s];
      IDX[((size_t)dir * NSYN + s) * NB + r] = jj[s];
    }
    const float bet = 1.0f / (1.0f + expf(-tn[r]));
    BETA[dir * NB + r] = bet;
    CB[dir * NB + r]   = (1.0f - bet) * bb[r];
  }
  if (rid < 2 * HID) {
    const int dir = rid >> 8, h = rid & (HID - 1);
    const float* tm = dir ? tau_m_bw : tau_m_fw;
    ALPHA[rid] = 1.0f / (1.0f + expf(-tm[h]));
  }
}

// ------------------------------------------------------- recurrent core ----
// grid = 64 (dir*32 + batch), block = 512 threads, thread t owns branches 4t..4t+3
__global__ __launch_bounds__(512, 2) void snn_recurrent(
    const float* __restrict__ x, const float* __restrict__ W,
    const u16* __restrict__ IDX, const float* __restrict__ BETA,
    const float* __restrict__ CB, const float* __restrict__ ALPHA,
    float* __restrict__ FRAMES)
{
  const int wg  = blockIdx.x;
  const int dir = wg >> 5, b = wg & 31;
  const int tid = threadIdx.x;
  const int r0  = tid * 4;

  __shared__ float ksh[KS];
  if (tid < KS) ksh[tid] = 0.0f;

  // register-resident weights + packed byte offsets
  float wv0[NSYN], wv1[NSYN], wv2[NSYN], wv3[NSYN];
  u32 op0[NSYN], op1[NSYN];
  const float* Wd = W + (size_t)dir * (NSYN * NB);
  const u16*  Id  = IDX + (size_t)dir * (NSYN * NB);
#pragma unroll
  for (int s = 0; s < NSYN; ++s) {
    const float4 w4 = *reinterpret_cast<const float4*>(Wd + s * NB + r0);
    wv0[s] = w4.x; wv1[s] = w4.y; wv2[s] = w4.z; wv3[s] = w4.w;
    const uint2 i4 = *reinterpret_cast<const uint2*>(Id + s * NB + r0);
    op0[s] = i4.x * 4u;   // (lo*4) | (hi*4)<<16  (no carry: idx*4 < 1184)
    op1[s] = i4.y * 4u;
  }
  const float4 be = *reinterpret_cast<const float4*>(BETA + dir * NB + r0);
  const float4 cb = *reinterpret_cast<const float4*>(CB + dir * NB + r0);
  const float alpha = ALPHA[dir * HID + (tid >> 1)];

  const float* xb = x + (size_t)b * (SFRAMES * 39);
  float* frow = FRAMES + ((size_t)(dir * 32 + b)) * (SFRAMES * HID) + (tid >> 1);

  float d0 = 0.f, d1 = 0.f, d2 = 0.f, d3 = 0.f;
  float mem = 0.f, spk = 0.f, facc = 0.f;

  const bool doin = (tid < 39);
  if (doin) ksh[tid] = xb[tid];          // frame 0
  __syncthreads();

  const char* kb = reinterpret_cast<const char*>(&ksh[0]);

#pragma unroll 1
  for (int st = 0; st < TSTEPS; ++st) {
    // prefetch next input frame element (latency hidden under gather)
    float xv = 0.f;
    if (doin) {
      int nf = (dir == 0) ? ((st + 1) / 10) : ((200 - (st + 10) / 10) % 200);
      if (nf > 199) nf = 199;
      xv = xb[nf * 39 + tid];
    }
    // sparse gather-dot: 4 branches x 37 synapses
    float a0 = 0.f, a1 = 0.f, a2 = 0.f, a3 = 0.f;
#pragma unroll
    for (int s = 0; s < NSYN; ++s) {
      const u32 p0 = op0[s], p1 = op1[s];
      a0 += wv0[s] * *reinterpret_cast<const float*>(kb + (p0 & 0xFFFFu));
      a1 += wv1[s] * *reinterpret_cast<const float*>(kb + (p0 >> 16));
      a2 += wv2[s] * *reinterpret_cast<const float*>(kb + (p1 & 0xFFFFu));
      a3 += wv3[s] * *reinterpret_cast<const float*>(kb + (p1 >> 16));
    }
    __syncthreads();   // all reads of k done before anyone rewrites it

    // d = beta*d + (1-beta)*acc + (1-beta)*bias  ==  beta*(d-acc) + acc + cb
    d0 = be.x * (d0 - a0) + (a0 + cb.x);
    d1 = be.y * (d1 - a1) + (a1 + cb.y);
    d2 = be.z * (d2 - a2) + (a2 + cb.z);
    d3 = be.w * (d3 - a3) + (a3 + cb.w);
    const float ps = d0 + d1 + d2 + d3;
    const float dsum = ps + __shfl_xor(ps, 1);
    // mem = alpha*mem + (1-alpha)*dsum - spk == alpha*(mem-dsum) + dsum - spk
    mem = alpha * (mem - dsum) + dsum - spk;
    spk = (mem > 1.0f) ? 1.0f : 0.0f;
    facc += spk;

    if ((tid & 1) == 0) ksh[39 + (tid >> 1)] = spk;   // publish spike
    if (doin) ksh[tid] = xv;                          // next input frame

    if ((st % 10) == 9) {
      if ((tid & 1) == 0) frow[(st / 10) * HID] = facc * 0.1f;
      facc = 0.f;
    }
    __syncthreads();   // k ready for next step
  }
}

// ------------------------------------------------------------- readout ----
// y[s,b,o] = b_ro[o] + merged(s,b,:) . w_ro[o,:]
__global__ void ro_matmul(const float* __restrict__ FRAMES,
                          const float* __restrict__ w_ro,
                          const float* __restrict__ b_ro,
                          float* __restrict__ Y)
{
  const int bid = blockIdx.x;          // s*32 + b
  const int s = bid >> 5, b = bid & 31;
  __shared__ float row[512];
  const float* Ff = FRAMES + ((size_t)(0 * 32 + b) * SFRAMES + s) * HID;
  const float* Fb = FRAMES + ((size_t)(1 * 32 + b) * SFRAMES + (SFRAMES - 1 - s)) * HID;
  for (int i = threadIdx.x; i < HID; i += 64) {
    row[i] = Ff[i];
    row[HID + i] = Fb[i];
  }
  __syncthreads();
  const int o = threadIdx.x;
  if (o < OUTC) {
    float acc = b_ro[o];
    const float* wr = w_ro + (size_t)o * 512;
#pragma unroll 8
    for (int k = 0; k < 512; ++k) acc += row[k] * wr[k];
    Y[(size_t)bid * OUTC + o] = acc;
  }
}

// readout leaky-integrator scan + log_softmax + NLL loss
__global__ void ro_scan(const float* __restrict__ Y,
                        const float* __restrict__ tau_ro,
                        const int* __restrict__ labels,
                        float* __restrict__ out)
{
  const int b = blockIdx.x;            // 32 blocks
  const int o = threadIdx.x;           // 64 threads
  __shared__ float mems[SFRAMES * 40];
  if (o < OUTC) {
    const float ar = 1.0f / (1.0f + expf(-tau_ro[o]));
    const float om = 1.0f - ar;
    float m = 0.0f;
    for (int s = 0; s < SFRAMES; ++s) {
      m = ar * m + om * Y[((size_t)s * 32 + b) * OUTC + o];
      mems[s * 40 + o] = m;
    }
  }
  __syncthreads();
  for (int s = threadIdx.x; s < SFRAMES; s += 64) {
    float mx = -1e30f;
    for (int j = 0; j < OUTC; ++j) mx = fmaxf(mx, mems[s * 40 + j]);
    float se = 0.0f;
    for (int j = 0; j < OUTC; ++j) se += expf(mems[s * 40 + j] - mx);
    const float lse = logf(se);
    float* op = out + ((size_t)s * 32 + b) * OUTC;
    for (int j = 0; j < OUTC; ++j) op[j] = mems[s * 40 + j] - mx - lse;
    const int lab = labels[b * SFRAMES + s];
    const float nll = -(mems[s * 40 + lab] - mx - lse);
    atomicAdd(out + SFRAMES * 32 * OUTC, nll * (1.0f / 32.0f));
  }
}

// -------------------------------------------------------------- launch ----
extern "C" void kernel_launch(void* const* d_in, const int* in_sizes, int n_in,
                              void* d_out, int out_size, void* d_ws, size_t ws_size,
                              hipStream_t stream)
{
  const float* x        = (const float*)d_in[0];
  const int*   labels   = (const int*)d_in[1];
  const float* w_fw     = (const float*)d_in[2];
  const float* b_fw     = (const float*)d_in[3];
  const float* tau_m_fw = (const float*)d_in[4];
  const float* tau_n_fw = (const float*)d_in[5];
  const float* mask_fw  = (const float*)d_in[6];
  const float* w_bw     = (const float*)d_in[7];
  const float* b_bw     = (const float*)d_in[8];
  const float* tau_m_bw = (const float*)d_in[9];
  const float* tau_n_bw = (const float*)d_in[10];
  const float* mask_bw  = (const float*)d_in[11];
  const float* w_ro     = (const float*)d_in[12];
  const float* b_ro     = (const float*)d_in[13];
  const float* tau_m_ro = (const float*)d_in[14];
  float* out = (float*)d_out;

  char* ws = (char*)d_ws;
  float* W      = (float*)(ws + WS_W);
  u16*   IDX    = (u16*)(ws + WS_IDX);
  float* BETA   = (float*)(ws + WS_BETA);
  float* CB     = (float*)(ws + WS_CB);
  float* ALPHA  = (float*)(ws + WS_ALPHA);
  float* FRAMES = (float*)(ws + WS_FRAMES);
  float* Y      = (float*)(ws + WS_Y);

  // zero the loss accumulator slot
  hipMemsetAsync(out + SFRAMES * 32 * OUTC, 0, sizeof(float), stream);

  build_sparse<<<16, 256, 0, stream>>>(w_fw, b_fw, tau_n_fw, mask_fw,
                                       w_bw, b_bw, tau_n_bw, mask_bw,
                                       tau_m_fw, tau_m_bw,
                                       W, IDX, BETA, CB, ALPHA);
  snn_recurrent<<<64, 512, 0, stream>>>(x, W, IDX, BETA, CB, ALPHA, FRAMES);
  ro_matmul<<<SFRAMES * 32, 64, 0, stream>>>(FRAMES, w_ro, b_ro, Y);
  ro_scan<<<32, 64, 0, stream>>>(Y, tau_m_ro, labels, out);
}

// Round 2
// 11006.107 us; speedup vs baseline: 1.0688x; 1.0688x over previous
//
#include <hip/hip_runtime.h>
#include <math.h>

typedef unsigned short u16;
typedef unsigned int u32;

#define NSYN 37
#define NB   2048
#define KS   296
#define TSTEPS 2000
#define SFRAMES 200
#define HID 256
#define OUTC 39
#define NREP 4
#define KW  (NREP*KS)        // 1184 floats of LDS (replicas at bank shifts 0,8,16,24)

// ws layout (byte offsets, all 16B aligned)
#define WS_W      0u          // float [2][37][2048]
#define WS_IDX    606208u     // u16   [2][37][2048]  (idx -> rewritten to byte offsets)
#define WS_BETA   909312u     // float [2][2048]
#define WS_CB     925696u     // float [2][2048]
#define WS_ALPHA  942080u     // float [2][256]
#define WS_FRAMES 944128u     // float [2][32][200][256]
#define WS_Y      14051328u   // float [200][32][39]

// ---------------------------------------------------------------- setup ----
__global__ void build_sparse(
    const float* __restrict__ w_fw, const float* __restrict__ b_fw,
    const float* __restrict__ tau_n_fw, const float* __restrict__ mask_fw,
    const float* __restrict__ w_bw, const float* __restrict__ b_bw,
    const float* __restrict__ tau_n_bw, const float* __restrict__ mask_bw,
    const float* __restrict__ tau_m_fw, const float* __restrict__ tau_m_bw,
    float* __restrict__ W, u16* __restrict__ IDX, float* __restrict__ BETA,
    float* __restrict__ CB, float* __restrict__ ALPHA)
{
  const int rid = blockIdx.x * 256 + threadIdx.x;
  if (rid < 2 * NB) {
    const int dir = rid >> 11, r = rid & (NB - 1);
    const float* w  = dir ? w_bw : w_fw;
    const float* mk = dir ? mask_bw : mask_fw;
    const float* bb = dir ? b_bw : b_fw;
    const float* tn = dir ? tau_n_bw : tau_n_fw;
    u16 jj[NSYN]; float wv[NSYN];
    int cnt = 0;
    for (int j = 0; j < KS; ++j) {
      const float m = mk[(size_t)r * KS + j];
      if (m != 0.0f && cnt < NSYN) { jj[cnt] = (u16)j; wv[cnt] = w[(size_t)r * KS + j]; ++cnt; }
    }
    for (; cnt < NSYN; ++cnt) { jj[cnt] = (u16)(KS - 1); wv[cnt] = 0.0f; }
    // base order: sort by bank rotated by branch index (spreads banks per slot)
    const int rot = r & 31;
    for (int i = 1; i < NSYN; ++i) {
      const u16 kj = jj[i]; const float kw = wv[i];
      const int key = ((kj & 31) - rot) & 31;
      int p = i - 1;
      while (p >= 0 && ((((jj[p] & 31) - rot) & 31) > key)) {
        jj[p + 1] = jj[p]; wv[p + 1] = wv[p]; --p;
      }
      jj[p + 1] = kj; wv[p + 1] = kw;
    }
    for (int s = 0; s < NSYN; ++s) {
      W[((size_t)dir * NSYN + s) * NB + r]   = wv[s];
      IDX[((size_t)dir * NSYN + s) * NB + r] = jj[s];
    }
    const float bet = 1.0f / (1.0f + expf(-tn[r]));
    BETA[dir * NB + r] = bet;
    CB[dir * NB + r]   = (1.0f - bet) * bb[r];
  }
  if (rid < 2 * HID) {
    const int dir = rid >> 8, h = rid & (HID - 1);
    const float* tm = dir ? tau_m_bw : tau_m_fw;
    ALPHA[rid] = 1.0f / (1.0f + expf(-tm[h]));
  }
}

// load-aware replica choice: per wave per gather-instruction, lanes pick one of
// 4 LDS replicas (bank shifts 0/8/16/24) keeping <=2 lanes per bank.
// Rewrites IDX (synapse index) into final LDS byte offsets.
__global__ void schedule_copies(u16* __restrict__ IDX)
{
  const int dir = blockIdx.x;
  const int tid = threadIdx.x;
  const int w = tid >> 6, l = tid & 63;
  __shared__ u32 cnt[8 * 32];
  if (tid < 256) cnt[tid] = 0;
  __syncthreads();
  u16* ID = IDX + (size_t)dir * (NSYN * NB);
  for (int s = 0; s < NSYN; ++s) {
    for (int j = 0; j < 4; ++j) {
      const int row = tid * 4 + j;
      const u32 idx = ID[s * NB + row];
      const u32 cpref = (u32)((l + s) & 3);
      int chosen = -1;
      for (int r = 0; r < 4; ++r) {
        if (chosen >= 0) break;
        const u32 c = (cpref + r) & 3;
        const u32 bank = (idx + 8u * c) & 31u;
        const u32 old = atomicAdd(&cnt[w * 32 + bank], 1u);
        if (old < 2u) chosen = (int)c;
        else atomicSub(&cnt[w * 32 + bank], 1u);
      }
      if (chosen < 0) chosen = (int)cpref;
      __syncthreads();
      ID[s * NB + row] = (u16)((((u32)chosen * KS + idx) * 4u));
      if (l < 32) cnt[w * 32 + l] = 0;
      __syncthreads();
    }
  }
}

// ------------------------------------------------------- recurrent core ----
// grid = 64 (dir*32 + batch), block = 512, thread t owns branches 4t..4t+3
__global__ __launch_bounds__(512, 1) void snn_recurrent(
    const float* __restrict__ x, const float* __restrict__ W,
    const u16* __restrict__ OFF, const float* __restrict__ BETA,
    const float* __restrict__ CB, const float* __restrict__ ALPHA,
    float* __restrict__ FRAMES)
{
  const int wg  = blockIdx.x;
  const int dir = wg >> 5, b = wg & 31;
  const int tid = threadIdx.x;
  const int r0  = tid * 4;

  __shared__ float ksh[KW];
  for (int i = tid; i < KW; i += 512) ksh[i] = 0.0f;

  // register-resident weights + final packed byte offsets (replica baked in)
  float wv0[NSYN], wv1[NSYN], wv2[NSYN], wv3[NSYN];
  u32 op0[NSYN], op1[NSYN];
  const float* Wd = W + (size_t)dir * (NSYN * NB);
  const u16*  Od  = OFF + (size_t)dir * (NSYN * NB);
#pragma unroll
  for (int s = 0; s < NSYN; ++s) {
    const float4 w4 = *reinterpret_cast<const float4*>(Wd + s * NB + r0);
    wv0[s] = w4.x; wv1[s] = w4.y; wv2[s] = w4.z; wv3[s] = w4.w;
    const uint2 i4 = *reinterpret_cast<const uint2*>(Od + s * NB + r0);
    op0[s] = i4.x;          // two u16 byte-offsets packed
    op1[s] = i4.y;
  }
  const float4 be = *reinterpret_cast<const float4*>(BETA + dir * NB + r0);
  const float4 cb = *reinterpret_cast<const float4*>(CB + dir * NB + r0);
  const float alpha = ALPHA[dir * HID + (tid >> 1)];

  const float* xb = x + (size_t)b * (SFRAMES * 39);
  float* frow = FRAMES + ((size_t)(dir * 32 + b)) * (SFRAMES * HID) + (tid >> 1);

  float d0 = 0.f, d1 = 0.f, d2 = 0.f, d3 = 0.f;
  float mem = 0.f, spk = 0.f, facc = 0.f;

  // frame 0 inputs into all replicas
  if (tid < 39) {
    const float xv = xb[tid];
#pragma unroll
    for (int c = 0; c < NREP; ++c) ksh[c * KS + tid] = xv;
  }
  __syncthreads();

  const char* kb  = reinterpret_cast<const char*>(&ksh[0]);

#pragma unroll 1
  for (int st = 0; st < TSTEPS; ++st) {
    // sparse gather-dot: 4 branches x 37 synapses, conflict-scheduled replicas
    float a0 = 0.f, a1 = 0.f, a2 = 0.f, a3 = 0.f;
#pragma unroll
    for (int s = 0; s < NSYN; ++s) {
      const u32 p0 = op0[s], p1 = op1[s];
      a0 += wv0[s] * *reinterpret_cast<const float*>(kb + (p0 & 0xFFFFu));
      a1 += wv1[s] * *reinterpret_cast<const float*>(kb + (p0 >> 16));
      a2 += wv2[s] * *reinterpret_cast<const float*>(kb + (p1 & 0xFFFFu));
      a3 += wv3[s] * *reinterpret_cast<const float*>(kb + (p1 >> 16));
    }
    __syncthreads();   // all reads of k done before anyone rewrites it

    d0 = be.x * (d0 - a0) + (a0 + cb.x);
    d1 = be.y * (d1 - a1) + (a1 + cb.y);
    d2 = be.z * (d2 - a2) + (a2 + cb.z);
    d3 = be.w * (d3 - a3) + (a3 + cb.w);
    const float ps = d0 + d1 + d2 + d3;
    const float dsum = ps + __shfl_xor(ps, 1);
    mem = alpha * (mem - dsum) + dsum - spk;
    spk = (mem > 1.0f) ? 1.0f : 0.0f;
    facc += spk;

    // publish spike to 2 of the 4 replicas (other neuron-thread does the rest)
    {
      const int n  = tid >> 1;
      const int c0 = (tid & 1) * 2;
      float* p = &ksh[c0 * KS + 39 + n];
      p[0]  = spk;
      p[KS] = spk;
    }

    if ((st % 10) == 9) {
      if ((tid & 1) == 0) frow[(st / 10) * HID] = facc * 0.1f;
      facc = 0.f;
      if (tid < 39) {
        int nf = (dir == 0) ? ((st + 10) / 10) : ((200 - (st + 10) / 10) % 200);
        if (nf > 199) nf = 0;   // st=1999: value never consumed
        const float xv = xb[nf * 39 + tid];
#pragma unroll
        for (int c = 0; c < NREP; ++c) ksh[c * KS + tid] = xv;
      }
    }
    __syncthreads();   // k ready for next step
  }
}

// ------------------------------------------------------------- readout ----
__global__ void ro_matmul(const float* __restrict__ FRAMES,
                          const float* __restrict__ w_ro,
                          const float* __restrict__ b_ro,
                          float* __restrict__ Y)
{
  const int bid = blockIdx.x;          // s*32 + b
  const int s = bid >> 5, b = bid & 31;
  __shared__ float row[512];
  const float* Ff = FRAMES + ((size_t)(0 * 32 + b) * SFRAMES + s) * HID;
  const float* Fb = FRAMES + ((size_t)(1 * 32 + b) * SFRAMES + (SFRAMES - 1 - s)) * HID;
  for (int i = threadIdx.x; i < HID; i += 64) {
    row[i] = Ff[i];
    row[HID + i] = Fb[i];
  }
  __syncthreads();
  const int o = threadIdx.x;
  if (o < OUTC) {
    float acc = b_ro[o];
    const float* wr = w_ro + (size_t)o * 512;
#pragma unroll 8
    for (int k = 0; k < 512; ++k) acc += row[k] * wr[k];
    Y[(size_t)bid * OUTC + o] = acc;
  }
}

__global__ void ro_scan(const float* __restrict__ Y,
                        const float* __restrict__ tau_ro,
                        const int* __restrict__ labels,
                        float* __restrict__ out)
{
  const int b = blockIdx.x;            // 32 blocks
  const int o = threadIdx.x;           // 64 threads
  __shared__ float mems[SFRAMES * 40];
  if (o < OUTC) {
    const float ar = 1.0f / (1.0f + expf(-tau_ro[o]));
    const float om = 1.0f - ar;
    float m = 0.0f;
    for (int s = 0; s < SFRAMES; ++s) {
      m = ar * m + om * Y[((size_t)s * 32 + b) * OUTC + o];
      mems[s * 40 + o] = m;
    }
  }
  __syncthreads();
  for (int s = threadIdx.x; s < SFRAMES; s += 64) {
    float mx = -1e30f;
    for (int j = 0; j < OUTC; ++j) mx = fmaxf(mx, mems[s * 40 + j]);
    float se = 0.0f;
    for (int j = 0; j < OUTC; ++j) se += expf(mems[s * 40 + j] - mx);
    const float lse = logf(se);
    float* op = out + ((size_t)s * 32 + b) * OUTC;
    for (int j = 0; j < OUTC; ++j) op[j] = mems[s * 40 + j] - mx - lse;
    const int lab = labels[b * SFRAMES + s];
    const float nll = -(mems[s * 40 + lab] - mx - lse);
    atomicAdd(out + SFRAMES * 32 * OUTC, nll * (1.0f / 32.0f));
  }
}

// -------------------------------------------------------------- launch ----
extern "C" void kernel_launch(void* const* d_in, const int* in_sizes, int n_in,
                              void* d_out, int out_size, void* d_ws, size_t ws_size,
                              hipStream_t stream)
{
  const float* x        = (const float*)d_in[0];
  const int*   labels   = (const int*)d_in[1];
  const float* w_fw     = (const float*)d_in[2];
  const float* b_fw     = (const float*)d_in[3];
  const float* tau_m_fw = (const float*)d_in[4];
  const float* tau_n_fw = (const float*)d_in[5];
  const float* mask_fw  = (const float*)d_in[6];
  const float* w_bw     = (const float*)d_in[7];
  const float* b_bw     = (const float*)d_in[8];
  const float* tau_m_bw = (const float*)d_in[9];
  const float* tau_n_bw = (const float*)d_in[10];
  const float* mask_bw  = (const float*)d_in[11];
  const float* w_ro     = (const float*)d_in[12];
  const float* b_ro     = (const float*)d_in[13];
  const float* tau_m_ro = (const float*)d_in[14];
  float* out = (float*)d_out;

  char* ws = (char*)d_ws;
  float* W      = (float*)(ws + WS_W);
  u16*   IDX    = (u16*)(ws + WS_IDX);
  float* BETA   = (float*)(ws + WS_BETA);
  float* CB     = (float*)(ws + WS_CB);
  float* ALPHA  = (float*)(ws + WS_ALPHA);
  float* FRAMES = (float*)(ws + WS_FRAMES);
  float* Y      = (float*)(ws + WS_Y);

  hipMemsetAsync(out + SFRAMES * 32 * OUTC, 0, sizeof(float), stream);

  build_sparse<<<16, 256, 0, stream>>>(w_fw, b_fw, tau_n_fw, mask_fw,
                                       w_bw, b_bw, tau_n_bw, mask_bw,
                                       tau_m_fw, tau_m_bw,
                                       W, IDX, BETA, CB, ALPHA);
  schedule_copies<<<2, 512, 0, stream>>>(IDX);
  snn_recurrent<<<64, 512, 0, stream>>>(x, W, IDX, BETA, CB, ALPHA, FRAMES);
  ro_matmul<<<SFRAMES * 32, 64, 0, stream>>>(FRAMES, w_ro, b_ro, Y);
  ro_scan<<<32, 64, 0, stream>>>(Y, tau_m_ro, labels, out);
}